// Round 3
// baseline (910.526 us; speedup 1.0000x reference)
//
#include <hip/hip_runtime.h>
#include <hip/hip_bf16.h>
#include <math.h>

#define BATCH   65536
#define IN_DIM  784
#define HID     256
#define LAT     32
#define NPROTO  25

typedef short  short8  __attribute__((ext_vector_type(8)));
typedef float  floatx4 __attribute__((ext_vector_type(4)));

// ---------------- bf16 split-3 helpers (proven numerics) ----------------
__device__ __forceinline__ unsigned short f2bf(float v) {
    __hip_bfloat16 b = __float2bfloat16(v);
    return *reinterpret_cast<unsigned short*>(&b);
}
__device__ __forceinline__ float bf2f(unsigned short u) {
    __hip_bfloat16 b = *reinterpret_cast<__hip_bfloat16*>(&u);
    return __bfloat162float(b);
}
__device__ __forceinline__ void split3(float v, unsigned short& o1,
                                       unsigned short& o2, unsigned short& o3) {
    o1 = f2bf(v); float r1 = v - bf2f(o1);
    o2 = f2bf(r1); float r2 = r1 - bf2f(o2);
    o3 = f2bf(r2);
}

__device__ __forceinline__ floatx4 mm_bf16(short8 a, short8 b, floatx4 c) {
    return __builtin_amdgcn_mfma_f32_16x16x32_bf16(a, b, c, 0, 0, 0);
}

// ================= MFMA path =================
// ws layout: B1 @0, B2 @409600, B3 @819200 (each 25*16*64*8 bf16 = 409600 B,
//            fragment-ordered), table @1228800 (25*784 f32)
#define BT_SHORTS  204800
#define WS_NEEDED  1307200

// B fragment order: frag f = (s*16 + n16), lane holds
//   We1[s*32 + (lane>>4)*8 + j][n16*16 + (lane&15)]  for j=0..7  (bf16 split-3)
// encoder loads each fragment with one coalesced 16B global load per array.
__global__ __launch_bounds__(256)
void prep_BF(const float* __restrict__ We1,
             unsigned short* __restrict__ B1,
             unsigned short* __restrict__ B2,
             unsigned short* __restrict__ B3)
{
    int t   = blockIdx.x * 256 + threadIdx.x;   // 0..25599
    int l15 = t & 15;
    int q   = (t >> 4) & 3;
    int sn  = t >> 6;
    int s   = sn >> 4;
    int n   = (sn & 15) * 16 + l15;
    int k0  = s * 32 + q * 8;
    short8 v1, v2, v3;
#pragma unroll
    for (int j = 0; j < 8; ++j) {
        int k = k0 + j;
        float v = (k < IN_DIM) ? We1[(size_t)k * HID + n] : 0.f;
        unsigned short a, b, c;
        split3(v, a, b, c);
        v1[j] = (short)a;
        v2[j] = (short)b;
        v3[j] = (short)c;
    }
    size_t o = (size_t)t * 8;
    *(short8*)(B1 + o) = v1;
    *(short8*)(B2 + o) = v2;
    *(short8*)(B3 + o) = v3;
}

// decoder table: table[p] = sigmoid(relu(p@Wd1+bd1)@Wd2+bd2)   (25 rows only)
__global__ __launch_bounds__(256)
void dpsom_dectab(const float* __restrict__ protos,
                  const float* __restrict__ Wd1,
                  const float* __restrict__ bd1,
                  const float* __restrict__ Wd2,
                  const float* __restrict__ bd2,
                  float* __restrict__ table)
{
    __shared__ float pr[LAT];
    __shared__ float hd[HID];
    const int p = blockIdx.x;
    const int tid = threadIdx.x;
    if (tid < LAT) pr[tid] = protos[p * LAT + tid];
    __syncthreads();
    float s = bd1[tid];
#pragma unroll
    for (int k = 0; k < LAT; ++k)
        s = fmaf(pr[k], Wd1[k * HID + tid], s);
    hd[tid] = fmaxf(s, 0.f);
    __syncthreads();
    for (int i = tid; i < IN_DIM; i += 256) {
        float o = bd2[i];
        for (int j = 0; j < HID; ++j)
            o = fmaf(hd[j], Wd2[(size_t)j * IN_DIM + i], o);
        table[p * IN_DIM + i] = 1.f / (1.f + expf(-o));
    }
}

// ---------------- encoder ----------------
// bf16 split-3 (6 MFMAs / K-product). Latency-scheduled K-loop:
//   - B fragments prefetched ONE FULL STEP ahead into registers (L2 latency hidden)
//   - x loaded at step top, converted/written AFTER the MFMA block (HBM latency hidden)
//   - A double-buffered in LDS with XOR chunk swizzle (measured conflict-free layout)
//   - one barrier per step
// LDS: A buf b @ b*12288: a1 +0, a2 +4096, a3 +8192  (64 rows x 64 B, chunk-swizzled)
// epilogue aliases: h_lds f32[32][260]@0, z_lds f32[64][33]@33280,
//                   cdist[64][4]@41728, cidx[64][4]@42752, minidx[64]@43776
#define AARR 4096
#define ABUF 12288

__device__ __forceinline__ void cvt_write3(float4 v0, float4 v1, char* wp) {
    float vv[8] = {v0.x, v0.y, v0.z, v0.w, v1.x, v1.y, v1.z, v1.w};
    short8 u1, u2, u3;
#pragma unroll
    for (int j = 0; j < 8; ++j) {
        unsigned short a, b, c;
        split3(vv[j], a, b, c);
        u1[j] = (short)a;
        u2[j] = (short)b;
        u3[j] = (short)c;
    }
    *(short8*)(wp)            = u1;
    *(short8*)(wp + AARR)     = u2;
    *(short8*)(wp + 2 * AARR) = u3;
}

__global__ __launch_bounds__(256, 3)
void dpsom_encoder_bf3(const float* __restrict__ x,
                       const unsigned short* __restrict__ B1g,
                       const unsigned short* __restrict__ B2g,
                       const unsigned short* __restrict__ B3g,
                       const float* __restrict__ be1,
                       const float* __restrict__ We2,
                       const float* __restrict__ be2,
                       const float* __restrict__ protos,
                       const float* __restrict__ table,
                       float* __restrict__ z_out,
                       float* __restrict__ somz_out,
                       float* __restrict__ xrec)
{
    __shared__ __align__(16) char smem[45056];
    const int tid  = threadIdx.x;
    const int wave = tid >> 6;
    const int lane = tid & 63;
    const int l15  = lane & 15;
    const int q    = lane >> 4;
    const int sw   = (l15 >> 1) & 3;          // read-side chunk swizzle
    const int row0 = blockIdx.x * 64;

    // A staging assignment: thread -> (row, 16B k-chunk), write-side swizzle
    const int arow = tid >> 2;
    const int aq   = tid & 3;
    const int awoff = arow * 64 + (aq ^ ((arow >> 1) & 3)) * 16;
    const float* xrow = x + (size_t)(row0 + arow) * IN_DIM + aq * 8;

    floatx4 acc[4][4];
#pragma unroll
    for (int i = 0; i < 4; ++i)
#pragma unroll
        for (int j = 0; j < 4; ++j) acc[i][j] = (floatx4)0.f;

    short8 bA1[4], bA2[4], bA3[4];    // B fragment double register set
    short8 bB1[4], bB2[4], bB3[4];

    // prologue: stage x(0) into buf0, load B(0) into bA
    {
        float4 v0 = *(const float4*)(xrow);
        float4 v1 = *(const float4*)(xrow + 4);
        cvt_write3(v0, v1, smem + awoff);
        const int fb = (wave * 4) << 9;
#pragma unroll
        for (int nf = 0; nf < 4; ++nf) {
            int off = fb + (nf << 9) + (lane << 3);
            bA1[nf] = *(const short8*)(B1g + off);
            bA2[nf] = *(const short8*)(B2g + off);
            bA3[nf] = *(const short8*)(B3g + off);
        }
    }
    __syncthreads();

    auto kstep = [&](int s,
                     short8 (&c1)[4], short8 (&c2)[4], short8 (&c3)[4],
                     short8 (&n1)[4], short8 (&n2)[4], short8 (&n3)[4]) {
        // prefetch B(s+1) -> registers (consumed next step; ~full step in flight)
        if (s < 24) {
            const int fb = ((s + 1) * 16 + wave * 4) << 9;
#pragma unroll
            for (int nf = 0; nf < 4; ++nf) {
                int off = fb + (nf << 9) + (lane << 3);
                n1[nf] = *(const short8*)(B1g + off);
                n2[nf] = *(const short8*)(B2g + off);
                n3[nf] = *(const short8*)(B3g + off);
            }
        }
        // x prefetch for step s+1 (consumed after the MFMA block)
        float4 v0 = make_float4(0.f, 0.f, 0.f, 0.f), v1 = v0;
        if (s < 24) {
            if ((s < 23) | (aq < 2)) {            // step 24 covers k=768..783 only
                v0 = *(const float4*)(xrow + (s + 1) * 32);
                v1 = *(const float4*)(xrow + (s + 1) * 32 + 4);
            }
        }
        // A fragments from LDS (chunk-swizzled, conflict-free)
        const char* abase = smem + (s & 1) * ABUF;
        short8 a1f[4], a2f[4], a3f[4];
#pragma unroll
        for (int mf = 0; mf < 4; ++mf) {
            const char* ap = abase + (16 * mf + l15) * 64 + ((q ^ sw) * 16);
            a1f[mf] = *(const short8*)ap;
            a2f[mf] = *(const short8*)(ap + AARR);
            a3f[mf] = *(const short8*)(ap + 2 * AARR);
        }
        // 96 MFMAs (6 split terms x 4 mf x 4 nf) on current-step B registers
#pragma unroll
        for (int nf = 0; nf < 4; ++nf) {
#pragma unroll
            for (int mf = 0; mf < 4; ++mf) acc[mf][nf] = mm_bf16(a1f[mf], c1[nf], acc[mf][nf]);
#pragma unroll
            for (int mf = 0; mf < 4; ++mf) acc[mf][nf] = mm_bf16(a1f[mf], c2[nf], acc[mf][nf]);
#pragma unroll
            for (int mf = 0; mf < 4; ++mf) acc[mf][nf] = mm_bf16(a2f[mf], c1[nf], acc[mf][nf]);
#pragma unroll
            for (int mf = 0; mf < 4; ++mf) acc[mf][nf] = mm_bf16(a1f[mf], c3[nf], acc[mf][nf]);
#pragma unroll
            for (int mf = 0; mf < 4; ++mf) acc[mf][nf] = mm_bf16(a3f[mf], c1[nf], acc[mf][nf]);
#pragma unroll
            for (int mf = 0; mf < 4; ++mf) acc[mf][nf] = mm_bf16(a2f[mf], c2[nf], acc[mf][nf]);
        }
        // stage x(s+1) into the other buffer (x load has had the MFMA phase to land)
        if (s < 24) cvt_write3(v0, v1, smem + ((s + 1) & 1) * ABUF + awoff);
        __syncthreads();
    };

    for (int sp = 0; sp < 12; ++sp) {
        kstep(2 * sp,     bA1, bA2, bA3, bB1, bB2, bB3);
        kstep(2 * sp + 1, bB1, bB2, bB3, bA1, bA2, bA3);
    }
    kstep(24, bA1, bA2, bA3, bB1, bB2, bB3);

    // bias + ReLU (C layout: row=16mf+4q+r, col=wave*64+16nf+l15)
    {
        float bias[4];
#pragma unroll
        for (int nf = 0; nf < 4; ++nf) bias[nf] = be1[wave * 64 + 16 * nf + l15];
#pragma unroll
        for (int mf = 0; mf < 4; ++mf)
#pragma unroll
            for (int nf = 0; nf < 4; ++nf)
#pragma unroll
                for (int r = 0; r < 4; ++r)
                    acc[mf][nf][r] = fmaxf(acc[mf][nf][r] + bias[nf], 0.f);
    }

    float* h_lds  = (float*)smem;             // [32][260]
    float* z_lds  = (float*)(smem + 33280);   // [64][33]
    float* cdist  = (float*)(smem + 41728);   // [64][4]
    int*   cidx   = (int*)  (smem + 42752);   // [64][4]
    int*   minidx = (int*)  (smem + 43776);   // [64]

    const int jz = tid & 31;
    const int rg = tid >> 5;
    const float bz = be2[jz];

    for (int hf = 0; hf < 2; ++hf) {
        __syncthreads();
#pragma unroll
        for (int mm = 0; mm < 2; ++mm) {
            int mf = 2 * hf + mm;
#pragma unroll
            for (int nf = 0; nf < 4; ++nf)
#pragma unroll
                for (int r = 0; r < 4; ++r) {
                    int lr = 16 * mm + 4 * q + r;
                    h_lds[lr * 260 + wave * 64 + 16 * nf + l15] = acc[mf][nf][r];
                }
        }
        __syncthreads();
        float s0 = bz, s1 = bz, s2 = bz, s3 = bz;
        const float* h0p = h_lds + (rg * 4 + 0) * 260;
        const float* h1p = h_lds + (rg * 4 + 1) * 260;
        const float* h2p = h_lds + (rg * 4 + 2) * 260;
        const float* h3p = h_lds + (rg * 4 + 3) * 260;
#pragma unroll 4
        for (int c = 0; c < HID; c += 4) {
            float w0 = We2[(c + 0) * LAT + jz];
            float w1 = We2[(c + 1) * LAT + jz];
            float w2 = We2[(c + 2) * LAT + jz];
            float w3 = We2[(c + 3) * LAT + jz];
            float4 h0 = *(const float4*)(h0p + c);
            float4 h1 = *(const float4*)(h1p + c);
            float4 h2 = *(const float4*)(h2p + c);
            float4 h3 = *(const float4*)(h3p + c);
            s0 = fmaf(h0.x, w0, fmaf(h0.y, w1, fmaf(h0.z, w2, fmaf(h0.w, w3, s0))));
            s1 = fmaf(h1.x, w0, fmaf(h1.y, w1, fmaf(h1.z, w2, fmaf(h1.w, w3, s1))));
            s2 = fmaf(h2.x, w0, fmaf(h2.y, w1, fmaf(h2.z, w2, fmaf(h2.w, w3, s2))));
            s3 = fmaf(h3.x, w0, fmaf(h3.y, w1, fmaf(h3.z, w2, fmaf(h3.w, w3, s3))));
        }
        int rbase = hf * 32 + rg * 4;
        z_lds[(rbase + 0) * 33 + jz] = s0;
        z_lds[(rbase + 1) * 33 + jz] = s1;
        z_lds[(rbase + 2) * 33 + jz] = s2;
        z_lds[(rbase + 3) * 33 + jz] = s3;
        z_out[(size_t)(row0 + rbase + 0) * LAT + jz] = s0;
        z_out[(size_t)(row0 + rbase + 1) * LAT + jz] = s1;
        z_out[(size_t)(row0 + rbase + 2) * LAT + jz] = s2;
        z_out[(size_t)(row0 + rbase + 3) * LAT + jz] = s3;
    }
    __syncthreads();

    // argmin over 25 prototypes, parallel over 4 proto-groups x 64 rows
    // (ascending group order + strict < preserves reference first-min tie-break)
    {
        const int r = tid & 63;
        const int g = tid >> 6;
        float zr[LAT];
        float zn = 0.f;
#pragma unroll
        for (int j = 0; j < LAT; ++j) {
            zr[j] = z_lds[r * 33 + j];
            zn = fmaf(zr[j], zr[j], zn);
        }
        const int p0 = (g == 0) ? 0 : (1 + g * 6);   // 0,7,13,19
        const int pc = (g == 0) ? 7 : 6;
        float best = 3.4e38f;
        int bp = p0;
        for (int pi = 0; pi < pc; ++pi) {
            int p = p0 + pi;
            float dot = 0.f, pn = 0.f;
#pragma unroll
            for (int j = 0; j < LAT; ++j) {
                float pv = protos[p * LAT + j];
                dot = fmaf(zr[j], pv, dot);
                pn  = fmaf(pv, pv, pn);
            }
            float d = zn - 2.f * dot + pn;
            if (d < best) { best = d; bp = p; }
        }
        cdist[r * 4 + g] = best;
        cidx[r * 4 + g]  = bp;
    }
    __syncthreads();
    if (tid < 64) {
        float best = cdist[tid * 4];
        int bp = cidx[tid * 4];
#pragma unroll
        for (int g = 1; g < 4; ++g) {
            float d = cdist[tid * 4 + g];
            if (d < best) { best = d; bp = cidx[tid * 4 + g]; }
        }
        minidx[tid] = bp;
    }
    __syncthreads();

    // som_z gather
#pragma unroll
    for (int m = 0; m < 8; ++m) {
        int r = rg * 8 + m;
        somz_out[(size_t)(row0 + r) * LAT + jz] = protos[minidx[r] * LAT + jz];
    }

    // fused x_recon: rows from decoder table (L2-hot), coalesced float4 stores
    for (int i2 = tid; i2 < 64 * 196; i2 += 256) {
        int row = i2 / 196;
        int c   = i2 - row * 196;
        int idx = minidx[row];
        ((float4*)xrec)[(size_t)(row0 + row) * 196 + c] =
            ((const float4*)table)[idx * 196 + c];
    }
}

// ================= fallback fp32 path (round-1, passed) =================
#define BMf 64
#define BKf 16
#define HSTRIDE 260
#define ZSTRIDE 33
#define SMEM_FLOATS 10432

__global__ __launch_bounds__(256)
void dpsom_encoder_fp32(const float* __restrict__ x,
                        const float* __restrict__ We1,
                        const float* __restrict__ be1,
                        const float* __restrict__ We2,
                        const float* __restrict__ be2,
                        const float* __restrict__ protos,
                        float* __restrict__ z_out,
                        float* __restrict__ somz_out,
                        int* __restrict__ minidx_out)
{
    __shared__ float smem[SMEM_FLOATS];
    __shared__ int minidx_lds[BMf];
    float* As = smem;
    float* Bs = smem + BKf * BMf;
    float* h_lds = smem;
    float* z_lds = smem + 32 * HSTRIDE;

    const int tid = threadIdx.x;
    const int tx = tid & 31;
    const int ty = tid >> 5;
    const int row0 = blockIdx.x * BMf;

    float acc[8][8];
#pragma unroll
    for (int i = 0; i < 8; ++i)
#pragma unroll
        for (int j = 0; j < 8; ++j) acc[i][j] = 0.f;

    const int ar  = tid >> 2;
    const int akq = tid & 3;

    for (int k0 = 0; k0 < IN_DIM; k0 += BKf) {
        __syncthreads();
        float4 av = *(const float4*)(x + (size_t)(row0 + ar) * IN_DIM + k0 + akq * 4);
        As[(akq * 4 + 0) * BMf + ar] = av.x;
        As[(akq * 4 + 1) * BMf + ar] = av.y;
        As[(akq * 4 + 2) * BMf + ar] = av.z;
        As[(akq * 4 + 3) * BMf + ar] = av.w;
#pragma unroll
        for (int i = 0; i < 4; ++i) {
            int f  = tid + i * 256;
            int bk = f >> 6;
            int bn = (f & 63) << 2;
            *(float4*)(Bs + bk * HID + bn) =
                *(const float4*)(We1 + (size_t)(k0 + bk) * HID + bn);
        }
        __syncthreads();
#pragma unroll
        for (int kk = 0; kk < BKf; ++kk) {
            float4 a0 = *(const float4*)(As + kk * BMf + ty * 8);
            float4 a1 = *(const float4*)(As + kk * BMf + ty * 8 + 4);
            float4 b0 = *(const float4*)(Bs + kk * HID + tx * 8);
            float4 b1 = *(const float4*)(Bs + kk * HID + tx * 8 + 4);
            float a[8] = {a0.x, a0.y, a0.z, a0.w, a1.x, a1.y, a1.z, a1.w};
            float b[8] = {b0.x, b0.y, b0.z, b0.w, b1.x, b1.y, b1.z, b1.w};
#pragma unroll
            for (int i = 0; i < 8; ++i)
#pragma unroll
                for (int j = 0; j < 8; ++j)
                    acc[i][j] = fmaf(a[i], b[j], acc[i][j]);
        }
    }
    {
        float bias[8];
#pragma unroll
        for (int j = 0; j < 8; ++j) bias[j] = be1[tx * 8 + j];
#pragma unroll
        for (int i = 0; i < 8; ++i)
#pragma unroll
            for (int j = 0; j < 8; ++j)
                acc[i][j] = fmaxf(acc[i][j] + bias[j], 0.f);
    }
    const int jz = tid & 31;
    const int rg = tid >> 5;
    const float bz = be2[jz];
    for (int hf = 0; hf < 2; ++hf) {
        __syncthreads();
        if ((ty >> 2) == hf) {
            int rb = (ty & 3) * 8;
#pragma unroll
            for (int i = 0; i < 8; ++i) {
                *(float4*)(h_lds + (rb + i) * HSTRIDE + tx * 8) =
                    make_float4(acc[i][0], acc[i][1], acc[i][2], acc[i][3]);
                *(float4*)(h_lds + (rb + i) * HSTRIDE + tx * 8 + 4) =
                    make_float4(acc[i][4], acc[i][5], acc[i][6], acc[i][7]);
            }
        }
        __syncthreads();
        float s0 = bz, s1 = bz, s2 = bz, s3 = bz;
        const float* h0p = h_lds + (rg * 4 + 0) * HSTRIDE;
        const float* h1p = h_lds + (rg * 4 + 1) * HSTRIDE;
        const float* h2p = h_lds + (rg * 4 + 2) * HSTRIDE;
        const float* h3p = h_lds + (rg * 4 + 3) * HSTRIDE;
#pragma unroll 4
        for (int c = 0; c < HID; c += 4) {
            float w0 = We2[(c + 0) * LAT + jz];
            float w1 = We2[(c + 1) * LAT + jz];
            float w2 = We2[(c + 2) * LAT + jz];
            float w3 = We2[(c + 3) * LAT + jz];
            float4 h0 = *(const float4*)(h0p + c);
            float4 h1 = *(const float4*)(h1p + c);
            float4 h2 = *(const float4*)(h2p + c);
            float4 h3 = *(const float4*)(h3p + c);
            s0 = fmaf(h0.x, w0, fmaf(h0.y, w1, fmaf(h0.z, w2, fmaf(h0.w, w3, s0))));
            s1 = fmaf(h1.x, w0, fmaf(h1.y, w1, fmaf(h1.z, w2, fmaf(h1.w, w3, s1))));
            s2 = fmaf(h2.x, w0, fmaf(h2.y, w1, fmaf(h2.z, w2, fmaf(h2.w, w3, s2))));
            s3 = fmaf(h3.x, w0, fmaf(h3.y, w1, fmaf(h3.z, w2, fmaf(h3.w, w3, s3))));
        }
        int rbase = hf * 32 + rg * 4;
        z_lds[(rbase + 0) * ZSTRIDE + jz] = s0;
        z_lds[(rbase + 1) * ZSTRIDE + jz] = s1;
        z_lds[(rbase + 2) * ZSTRIDE + jz] = s2;
        z_lds[(rbase + 3) * ZSTRIDE + jz] = s3;
        z_out[(size_t)(row0 + rbase + 0) * LAT + jz] = s0;
        z_out[(size_t)(row0 + rbase + 1) * LAT + jz] = s1;
        z_out[(size_t)(row0 + rbase + 2) * LAT + jz] = s2;
        z_out[(size_t)(row0 + rbase + 3) * LAT + jz] = s3;
    }
    __syncthreads();
    if (tid < BMf) {
        float zr[LAT];
        float zn = 0.f;
#pragma unroll
        for (int j = 0; j < LAT; ++j) {
            zr[j] = z_lds[tid * ZSTRIDE + j];
            zn = fmaf(zr[j], zr[j], zn);
        }
        float best = 3.4e38f;
        int bp = 0;
        for (int p = 0; p < NPROTO; ++p) {
            float dot = 0.f, pn = 0.f;
#pragma unroll
            for (int j = 0; j < LAT; ++j) {
                float pv = protos[p * LAT + j];
                dot = fmaf(zr[j], pv, dot);
                pn  = fmaf(pv, pv, pn);
            }
            float d = zn - 2.f * dot + pn;
            if (d < best) { best = d; bp = p; }
        }
        minidx_out[row0 + tid] = bp;
        minidx_lds[tid] = bp;
    }
    __syncthreads();
#pragma unroll
    for (int m = 0; m < 8; ++m) {
        int r = rg * 8 + m;
        somz_out[(size_t)(row0 + r) * LAT + jz] = protos[minidx_lds[r] * LAT + jz];
    }
}

__global__ __launch_bounds__(256)
void dpsom_gather(const float4* __restrict__ table,
                  const int* __restrict__ minidx,
                  float4* __restrict__ xrec)
{
    const int f = blockIdx.x * 256 + threadIdx.x;
    const int row = f / 196;
    const int c4  = f - row * 196;
    const int idx = minidx[row];
    xrec[f] = table[idx * 196 + c4];
}

// ================= launch =================
extern "C" void kernel_launch(void* const* d_in, const int* in_sizes, int n_in,
                              void* d_out, int out_size, void* d_ws, size_t ws_size,
                              hipStream_t stream)
{
    const float* x    = (const float*)d_in[0];
    const float* We1  = (const float*)d_in[1];
    const float* be1  = (const float*)d_in[2];
    const float* We2  = (const float*)d_in[3];
    const float* be2  = (const float*)d_in[4];
    const float* Wd1  = (const float*)d_in[5];
    const float* bd1  = (const float*)d_in[6];
    const float* Wd2  = (const float*)d_in[7];
    const float* bd2  = (const float*)d_in[8];
    const float* prot = (const float*)d_in[9];

    float* out   = (float*)d_out;
    float* xrec  = out;
    float* z_out = out + (size_t)BATCH * IN_DIM;
    float* somz  = z_out + (size_t)BATCH * LAT;

    if (ws_size >= WS_NEEDED) {
        unsigned short* B1 = (unsigned short*)d_ws;
        unsigned short* B2 = B1 + BT_SHORTS;
        unsigned short* B3 = B2 + BT_SHORTS;
        float* table = (float*)((char*)d_ws + 1228800);

        hipLaunchKernelGGL(prep_BF, dim3(100), dim3(256), 0, stream, We1, B1, B2, B3);
        hipLaunchKernelGGL(dpsom_dectab, dim3(NPROTO), dim3(256), 0, stream,
                           prot, Wd1, bd1, Wd2, bd2, table);
        hipLaunchKernelGGL(dpsom_encoder_bf3, dim3(BATCH / 64), dim3(256), 0, stream,
                           x, B1, B2, B3, be1, We2, be2, prot, table,
                           z_out, somz, xrec);
    } else {
        int*   minidx = (int*)d_ws;
        float* table  = (float*)((char*)d_ws + (size_t)BATCH * 4);
        hipLaunchKernelGGL(dpsom_encoder_fp32, dim3(BATCH / BMf), dim3(256), 0, stream,
                           x, We1, be1, We2, be2, prot, z_out, somz, minidx);
        hipLaunchKernelGGL(dpsom_dectab, dim3(NPROTO), dim3(256), 0, stream,
                           prot, Wd1, bd1, Wd2, bd2, table);
        hipLaunchKernelGGL(dpsom_gather, dim3((BATCH * (IN_DIM / 4)) / 256), dim3(256), 0, stream,
                           (const float4*)table, minidx, (float4*)xrec);
    }
}

// Round 4
// 494.093 us; speedup vs baseline: 1.8428x; 1.8428x over previous
//
#include <hip/hip_runtime.h>
#include <hip/hip_bf16.h>
#include <math.h>

#define BATCH   65536
#define IN_DIM  784
#define HID     256
#define LAT     32
#define NPROTO  25

typedef short  short8  __attribute__((ext_vector_type(8)));
typedef float  floatx4 __attribute__((ext_vector_type(4)));

// ---------------- bf16 split-3 helpers (proven numerics) ----------------
__device__ __forceinline__ unsigned short f2bf(float v) {
    __hip_bfloat16 b = __float2bfloat16(v);
    return *reinterpret_cast<unsigned short*>(&b);
}
__device__ __forceinline__ float bf2f(unsigned short u) {
    __hip_bfloat16 b = *reinterpret_cast<__hip_bfloat16*>(&u);
    return __bfloat162float(b);
}
__device__ __forceinline__ void split3(float v, unsigned short& o1,
                                       unsigned short& o2, unsigned short& o3) {
    o1 = f2bf(v); float r1 = v - bf2f(o1);
    o2 = f2bf(r1); float r2 = r1 - bf2f(o2);
    o3 = f2bf(r2);
}

__device__ __forceinline__ floatx4 mm_bf16(short8 a, short8 b, floatx4 c) {
    return __builtin_amdgcn_mfma_f32_16x16x32_bf16(a, b, c, 0, 0, 0);
}

// ================= MFMA path =================
// ws layout: B1 @0, B2 @409600, B3 @819200 (each 25*16*64*8 bf16 = 409600 B,
//            fragment-ordered), table @1228800 (25*784 f32)
#define BT_SHORTS  204800
#define WS_NEEDED  1307200

// B fragment order: frag f = (s*16 + n16), lane holds
//   We1[s*32 + (lane>>4)*8 + j][n16*16 + (lane&15)]  for j=0..7  (bf16 split-3)
__global__ __launch_bounds__(256)
void prep_BF(const float* __restrict__ We1,
             unsigned short* __restrict__ B1,
             unsigned short* __restrict__ B2,
             unsigned short* __restrict__ B3)
{
    int t   = blockIdx.x * 256 + threadIdx.x;   // 0..25599
    int l15 = t & 15;
    int q   = (t >> 4) & 3;
    int sn  = t >> 6;
    int s   = sn >> 4;
    int n   = (sn & 15) * 16 + l15;
    int k0  = s * 32 + q * 8;
    short8 v1, v2, v3;
#pragma unroll
    for (int j = 0; j < 8; ++j) {
        int k = k0 + j;
        float v = (k < IN_DIM) ? We1[(size_t)k * HID + n] : 0.f;
        unsigned short a, b, c;
        split3(v, a, b, c);
        v1[j] = (short)a;
        v2[j] = (short)b;
        v3[j] = (short)c;
    }
    size_t o = (size_t)t * 8;
    *(short8*)(B1 + o) = v1;
    *(short8*)(B2 + o) = v2;
    *(short8*)(B3 + o) = v3;
}

// decoder table: table[p] = sigmoid(relu(p@Wd1+bd1)@Wd2+bd2)   (25 rows only)
__global__ __launch_bounds__(256)
void dpsom_dectab(const float* __restrict__ protos,
                  const float* __restrict__ Wd1,
                  const float* __restrict__ bd1,
                  const float* __restrict__ Wd2,
                  const float* __restrict__ bd2,
                  float* __restrict__ table)
{
    __shared__ float pr[LAT];
    __shared__ float hd[HID];
    const int p = blockIdx.x;
    const int tid = threadIdx.x;
    if (tid < LAT) pr[tid] = protos[p * LAT + tid];
    __syncthreads();
    float s = bd1[tid];
#pragma unroll
    for (int k = 0; k < LAT; ++k)
        s = fmaf(pr[k], Wd1[k * HID + tid], s);
    hd[tid] = fmaxf(s, 0.f);
    __syncthreads();
    for (int i = tid; i < IN_DIM; i += 256) {
        float o = bd2[i];
        for (int j = 0; j < HID; ++j)
            o = fmaf(hd[j], Wd2[(size_t)j * IN_DIM + i], o);
        table[p * IN_DIM + i] = 1.f / (1.f + expf(-o));
    }
}

// ---------------- encoder ----------------
// bf16 split-3 (6 MFMAs / K-product). Latency-scheduled K-loop:
//   - B fragments prefetched ONE FULL STEP ahead into a ping-pong register pair
//     (macro-expanded step body: no lambdas, no reference-passed arrays -> no scratch)
//   - x loaded at step top, converted/written AFTER the MFMA block
//   - A double-buffered in LDS with XOR chunk swizzle (measured conflict-free)
//   - one barrier per step
// LDS: A buf b @ b*12288: a1 +0, a2 +4096, a3 +8192  (64 rows x 64 B, chunk-swizzled)
// epilogue aliases: h_lds f32[32][260]@0, z_lds f32[64][33]@33280,
//                   cdist[64][4]@41728, cidx[64][4]@42752, minidx[64]@43776
#define AARR 4096
#define ABUF 12288

__device__ __forceinline__ void cvt_write3(float4 v0, float4 v1, char* wp) {
    float vv[8] = {v0.x, v0.y, v0.z, v0.w, v1.x, v1.y, v1.z, v1.w};
    short8 u1, u2, u3;
#pragma unroll
    for (int j = 0; j < 8; ++j) {
        unsigned short a, b, c;
        split3(vv[j], a, b, c);
        u1[j] = (short)a;
        u2[j] = (short)b;
        u3[j] = (short)c;
    }
    *(short8*)(wp)            = u1;
    *(short8*)(wp + AARR)     = u2;
    *(short8*)(wp + 2 * AARR) = u3;
}

// one K-step: consume B regs C1/C2/C3, prefetch next step into N1/N2/N3
#define KSTEP(S, C1, C2, C3, N1, N2, N3)                                        \
  {                                                                             \
    const int s_ = (S);                                                         \
    if (s_ < 24) {                                                              \
      const int fbn_ = ((s_ + 1) * 16 + wave * 4) << 9;                         \
      _Pragma("unroll")                                                         \
      for (int nf = 0; nf < 4; ++nf) {                                          \
        int off_ = fbn_ + (nf << 9) + (lane << 3);                              \
        N1[nf] = *(const short8*)(B1g + off_);                                  \
        N2[nf] = *(const short8*)(B2g + off_);                                  \
        N3[nf] = *(const short8*)(B3g + off_);                                  \
      }                                                                         \
    }                                                                           \
    float4 xv0_ = make_float4(0.f, 0.f, 0.f, 0.f), xv1_ = xv0_;                 \
    if (s_ < 24) {                                                              \
      if ((s_ < 23) | (aq < 2)) {                                               \
        xv0_ = *(const float4*)(xrow + (s_ + 1) * 32);                          \
        xv1_ = *(const float4*)(xrow + (s_ + 1) * 32 + 4);                      \
      }                                                                         \
    }                                                                           \
    const char* abase_ = smem + (s_ & 1) * ABUF;                                \
    short8 a1f_[4], a2f_[4], a3f_[4];                                           \
    _Pragma("unroll")                                                           \
    for (int mf = 0; mf < 4; ++mf) {                                            \
      const char* ap_ = abase_ + (16 * mf + l15) * 64 + ((q ^ sw) * 16);        \
      a1f_[mf] = *(const short8*)ap_;                                           \
      a2f_[mf] = *(const short8*)(ap_ + AARR);                                  \
      a3f_[mf] = *(const short8*)(ap_ + 2 * AARR);                              \
    }                                                                           \
    _Pragma("unroll")                                                           \
    for (int nf = 0; nf < 4; ++nf) {                                            \
      _Pragma("unroll")                                                         \
      for (int mf = 0; mf < 4; ++mf) acc[mf][nf] = mm_bf16(a1f_[mf], C1[nf], acc[mf][nf]); \
      _Pragma("unroll")                                                         \
      for (int mf = 0; mf < 4; ++mf) acc[mf][nf] = mm_bf16(a1f_[mf], C2[nf], acc[mf][nf]); \
      _Pragma("unroll")                                                         \
      for (int mf = 0; mf < 4; ++mf) acc[mf][nf] = mm_bf16(a2f_[mf], C1[nf], acc[mf][nf]); \
      _Pragma("unroll")                                                         \
      for (int mf = 0; mf < 4; ++mf) acc[mf][nf] = mm_bf16(a1f_[mf], C3[nf], acc[mf][nf]); \
      _Pragma("unroll")                                                         \
      for (int mf = 0; mf < 4; ++mf) acc[mf][nf] = mm_bf16(a3f_[mf], C1[nf], acc[mf][nf]); \
      _Pragma("unroll")                                                         \
      for (int mf = 0; mf < 4; ++mf) acc[mf][nf] = mm_bf16(a2f_[mf], C2[nf], acc[mf][nf]); \
    }                                                                           \
    if (s_ < 24) cvt_write3(xv0_, xv1_, smem + ((s_ + 1) & 1) * ABUF + awoff);  \
    __syncthreads();                                                            \
  }

__global__ __launch_bounds__(256, 2)
void dpsom_encoder_bf3(const float* __restrict__ x,
                       const unsigned short* __restrict__ B1g,
                       const unsigned short* __restrict__ B2g,
                       const unsigned short* __restrict__ B3g,
                       const float* __restrict__ be1,
                       const float* __restrict__ We2,
                       const float* __restrict__ be2,
                       const float* __restrict__ protos,
                       const float* __restrict__ table,
                       float* __restrict__ z_out,
                       float* __restrict__ somz_out,
                       float* __restrict__ xrec)
{
    __shared__ __align__(16) char smem[45056];
    const int tid  = threadIdx.x;
    const int wave = tid >> 6;
    const int lane = tid & 63;
    const int l15  = lane & 15;
    const int q    = lane >> 4;
    const int sw   = (l15 >> 1) & 3;          // read-side chunk swizzle
    const int row0 = blockIdx.x * 64;

    // A staging assignment: thread -> (row, 16B k-chunk), write-side swizzle
    const int arow = tid >> 2;
    const int aq   = tid & 3;
    const int awoff = arow * 64 + (aq ^ ((arow >> 1) & 3)) * 16;
    const float* xrow = x + (size_t)(row0 + arow) * IN_DIM + aq * 8;

    floatx4 acc[4][4];
#pragma unroll
    for (int i = 0; i < 4; ++i)
#pragma unroll
        for (int j = 0; j < 4; ++j) acc[i][j] = (floatx4)0.f;

    short8 bA1[4], bA2[4], bA3[4];    // B fragment ping-pong register sets
    short8 bB1[4], bB2[4], bB3[4];

    // prologue: stage x(0) into buf0, load B(0) into bA
    {
        float4 v0 = *(const float4*)(xrow);
        float4 v1 = *(const float4*)(xrow + 4);
        cvt_write3(v0, v1, smem + awoff);
        const int fb = (wave * 4) << 9;
#pragma unroll
        for (int nf = 0; nf < 4; ++nf) {
            int off = fb + (nf << 9) + (lane << 3);
            bA1[nf] = *(const short8*)(B1g + off);
            bA2[nf] = *(const short8*)(B2g + off);
            bA3[nf] = *(const short8*)(B3g + off);
        }
    }
    __syncthreads();

    for (int sp = 0; sp < 12; ++sp) {
        KSTEP(2 * sp,     bA1, bA2, bA3, bB1, bB2, bB3);
        KSTEP(2 * sp + 1, bB1, bB2, bB3, bA1, bA2, bA3);
    }
    KSTEP(24, bA1, bA2, bA3, bB1, bB2, bB3);

    // bias + ReLU (C layout: row=16mf+4q+r, col=wave*64+16nf+l15)
    {
        float bias[4];
#pragma unroll
        for (int nf = 0; nf < 4; ++nf) bias[nf] = be1[wave * 64 + 16 * nf + l15];
#pragma unroll
        for (int mf = 0; mf < 4; ++mf)
#pragma unroll
            for (int nf = 0; nf < 4; ++nf)
#pragma unroll
                for (int r = 0; r < 4; ++r)
                    acc[mf][nf][r] = fmaxf(acc[mf][nf][r] + bias[nf], 0.f);
    }

    float* h_lds  = (float*)smem;             // [32][260]
    float* z_lds  = (float*)(smem + 33280);   // [64][33]
    float* cdist  = (float*)(smem + 41728);   // [64][4]
    int*   cidx   = (int*)  (smem + 42752);   // [64][4]
    int*   minidx = (int*)  (smem + 43776);   // [64]

    const int jz = tid & 31;
    const int rg = tid >> 5;
    const float bz = be2[jz];

    for (int hf = 0; hf < 2; ++hf) {
        __syncthreads();
#pragma unroll
        for (int mm = 0; mm < 2; ++mm) {
            int mf = 2 * hf + mm;
#pragma unroll
            for (int nf = 0; nf < 4; ++nf)
#pragma unroll
                for (int r = 0; r < 4; ++r) {
                    int lr = 16 * mm + 4 * q + r;
                    h_lds[lr * 260 + wave * 64 + 16 * nf + l15] = acc[mf][nf][r];
                }
        }
        __syncthreads();
        float s0 = bz, s1 = bz, s2 = bz, s3 = bz;
        const float* h0p = h_lds + (rg * 4 + 0) * 260;
        const float* h1p = h_lds + (rg * 4 + 1) * 260;
        const float* h2p = h_lds + (rg * 4 + 2) * 260;
        const float* h3p = h_lds + (rg * 4 + 3) * 260;
#pragma unroll 4
        for (int c = 0; c < HID; c += 4) {
            float w0 = We2[(c + 0) * LAT + jz];
            float w1 = We2[(c + 1) * LAT + jz];
            float w2 = We2[(c + 2) * LAT + jz];
            float w3 = We2[(c + 3) * LAT + jz];
            float4 h0 = *(const float4*)(h0p + c);
            float4 h1 = *(const float4*)(h1p + c);
            float4 h2 = *(const float4*)(h2p + c);
            float4 h3 = *(const float4*)(h3p + c);
            s0 = fmaf(h0.x, w0, fmaf(h0.y, w1, fmaf(h0.z, w2, fmaf(h0.w, w3, s0))));
            s1 = fmaf(h1.x, w0, fmaf(h1.y, w1, fmaf(h1.z, w2, fmaf(h1.w, w3, s1))));
            s2 = fmaf(h2.x, w0, fmaf(h2.y, w1, fmaf(h2.z, w2, fmaf(h2.w, w3, s2))));
            s3 = fmaf(h3.x, w0, fmaf(h3.y, w1, fmaf(h3.z, w2, fmaf(h3.w, w3, s3))));
        }
        int rbase = hf * 32 + rg * 4;
        z_lds[(rbase + 0) * 33 + jz] = s0;
        z_lds[(rbase + 1) * 33 + jz] = s1;
        z_lds[(rbase + 2) * 33 + jz] = s2;
        z_lds[(rbase + 3) * 33 + jz] = s3;
        z_out[(size_t)(row0 + rbase + 0) * LAT + jz] = s0;
        z_out[(size_t)(row0 + rbase + 1) * LAT + jz] = s1;
        z_out[(size_t)(row0 + rbase + 2) * LAT + jz] = s2;
        z_out[(size_t)(row0 + rbase + 3) * LAT + jz] = s3;
    }
    __syncthreads();

    // argmin over 25 prototypes, parallel over 4 proto-groups x 64 rows
    // (ascending group order + strict < preserves reference first-min tie-break)
    {
        const int r = tid & 63;
        const int g = tid >> 6;
        float zr[LAT];
        float zn = 0.f;
#pragma unroll
        for (int j = 0; j < LAT; ++j) {
            zr[j] = z_lds[r * 33 + j];
            zn = fmaf(zr[j], zr[j], zn);
        }
        const int p0 = (g == 0) ? 0 : (1 + g * 6);   // 0,7,13,19
        const int pc = (g == 0) ? 7 : 6;
        float best = 3.4e38f;
        int bp = p0;
        for (int pi = 0; pi < pc; ++pi) {
            int p = p0 + pi;
            float dot = 0.f, pn = 0.f;
#pragma unroll
            for (int j = 0; j < LAT; ++j) {
                float pv = protos[p * LAT + j];
                dot = fmaf(zr[j], pv, dot);
                pn  = fmaf(pv, pv, pn);
            }
            float d = zn - 2.f * dot + pn;
            if (d < best) { best = d; bp = p; }
        }
        cdist[r * 4 + g] = best;
        cidx[r * 4 + g]  = bp;
    }
    __syncthreads();
    if (tid < 64) {
        float best = cdist[tid * 4];
        int bp = cidx[tid * 4];
#pragma unroll
        for (int g = 1; g < 4; ++g) {
            float d = cdist[tid * 4 + g];
            if (d < best) { best = d; bp = cidx[tid * 4 + g]; }
        }
        minidx[tid] = bp;
    }
    __syncthreads();

    // som_z gather
#pragma unroll
    for (int m = 0; m < 8; ++m) {
        int r = rg * 8 + m;
        somz_out[(size_t)(row0 + r) * LAT + jz] = protos[minidx[r] * LAT + jz];
    }

    // fused x_recon: rows from decoder table (L2-hot), coalesced float4 stores
    for (int i2 = tid; i2 < 64 * 196; i2 += 256) {
        int row = i2 / 196;
        int c   = i2 - row * 196;
        int idx = minidx[row];
        ((float4*)xrec)[(size_t)(row0 + row) * 196 + c] =
            ((const float4*)table)[idx * 196 + c];
    }
}

// ================= fallback fp32 path (round-1, passed) =================
#define BMf 64
#define BKf 16
#define HSTRIDE 260
#define ZSTRIDE 33
#define SMEM_FLOATS 10432

__global__ __launch_bounds__(256)
void dpsom_encoder_fp32(const float* __restrict__ x,
                        const float* __restrict__ We1,
                        const float* __restrict__ be1,
                        const float* __restrict__ We2,
                        const float* __restrict__ be2,
                        const float* __restrict__ protos,
                        float* __restrict__ z_out,
                        float* __restrict__ somz_out,
                        int* __restrict__ minidx_out)
{
    __shared__ float smem[SMEM_FLOATS];
    __shared__ int minidx_lds[BMf];
    float* As = smem;
    float* Bs = smem + BKf * BMf;
    float* h_lds = smem;
    float* z_lds = smem + 32 * HSTRIDE;

    const int tid = threadIdx.x;
    const int tx = tid & 31;
    const int ty = tid >> 5;
    const int row0 = blockIdx.x * BMf;

    float acc[8][8];
#pragma unroll
    for (int i = 0; i < 8; ++i)
#pragma unroll
        for (int j = 0; j < 8; ++j) acc[i][j] = 0.f;

    const int ar  = tid >> 2;
    const int akq = tid & 3;

    for (int k0 = 0; k0 < IN_DIM; k0 += BKf) {
        __syncthreads();
        float4 av = *(const float4*)(x + (size_t)(row0 + ar) * IN_DIM + k0 + akq * 4);
        As[(akq * 4 + 0) * BMf + ar] = av.x;
        As[(akq * 4 + 1) * BMf + ar] = av.y;
        As[(akq * 4 + 2) * BMf + ar] = av.z;
        As[(akq * 4 + 3) * BMf + ar] = av.w;
#pragma unroll
        for (int i = 0; i < 4; ++i) {
            int f  = tid + i * 256;
            int bk = f >> 6;
            int bn = (f & 63) << 2;
            *(float4*)(Bs + bk * HID + bn) =
                *(const float4*)(We1 + (size_t)(k0 + bk) * HID + bn);
        }
        __syncthreads();
#pragma unroll
        for (int kk = 0; kk < BKf; ++kk) {
            float4 a0 = *(const float4*)(As + kk * BMf + ty * 8);
            float4 a1 = *(const float4*)(As + kk * BMf + ty * 8 + 4);
            float4 b0 = *(const float4*)(Bs + kk * HID + tx * 8);
            float4 b1 = *(const float4*)(Bs + kk * HID + tx * 8 + 4);
            float a[8] = {a0.x, a0.y, a0.z, a0.w, a1.x, a1.y, a1.z, a1.w};
            float b[8] = {b0.x, b0.y, b0.z, b0.w, b1.x, b1.y, b1.z, b1.w};
#pragma unroll
            for (int i = 0; i < 8; ++i)
#pragma unroll
                for (int j = 0; j < 8; ++j)
                    acc[i][j] = fmaf(a[i], b[j], acc[i][j]);
        }
    }
    {
        float bias[8];
#pragma unroll
        for (int j = 0; j < 8; ++j) bias[j] = be1[tx * 8 + j];
#pragma unroll
        for (int i = 0; i < 8; ++i)
#pragma unroll
            for (int j = 0; j < 8; ++j)
                acc[i][j] = fmaxf(acc[i][j] + bias[j], 0.f);
    }
    const int jz = tid & 31;
    const int rg = tid >> 5;
    const float bz = be2[jz];
    for (int hf = 0; hf < 2; ++hf) {
        __syncthreads();
        if ((ty >> 2) == hf) {
            int rb = (ty & 3) * 8;
#pragma unroll
            for (int i = 0; i < 8; ++i) {
                *(float4*)(h_lds + (rb + i) * HSTRIDE + tx * 8) =
                    make_float4(acc[i][0], acc[i][1], acc[i][2], acc[i][3]);
                *(float4*)(h_lds + (rb + i) * HSTRIDE + tx * 8 + 4) =
                    make_float4(acc[i][4], acc[i][5], acc[i][6], acc[i][7]);
            }
        }
        __syncthreads();
        float s0 = bz, s1 = bz, s2 = bz, s3 = bz;
        const float* h0p = h_lds + (rg * 4 + 0) * HSTRIDE;
        const float* h1p = h_lds + (rg * 4 + 1) * HSTRIDE;
        const float* h2p = h_lds + (rg * 4 + 2) * HSTRIDE;
        const float* h3p = h_lds + (rg * 4 + 3) * HSTRIDE;
#pragma unroll 4
        for (int c = 0; c < HID; c += 4) {
            float w0 = We2[(c + 0) * LAT + jz];
            float w1 = We2[(c + 1) * LAT + jz];
            float w2 = We2[(c + 2) * LAT + jz];
            float w3 = We2[(c + 3) * LAT + jz];
            float4 h0 = *(const float4*)(h0p + c);
            float4 h1 = *(const float4*)(h1p + c);
            float4 h2 = *(const float4*)(h2p + c);
            float4 h3 = *(const float4*)(h3p + c);
            s0 = fmaf(h0.x, w0, fmaf(h0.y, w1, fmaf(h0.z, w2, fmaf(h0.w, w3, s0))));
            s1 = fmaf(h1.x, w0, fmaf(h1.y, w1, fmaf(h1.z, w2, fmaf(h1.w, w3, s1))));
            s2 = fmaf(h2.x, w0, fmaf(h2.y, w1, fmaf(h2.z, w2, fmaf(h2.w, w3, s2))));
            s3 = fmaf(h3.x, w0, fmaf(h3.y, w1, fmaf(h3.z, w2, fmaf(h3.w, w3, s3))));
        }
        int rbase = hf * 32 + rg * 4;
        z_lds[(rbase + 0) * ZSTRIDE + jz] = s0;
        z_lds[(rbase + 1) * ZSTRIDE + jz] = s1;
        z_lds[(rbase + 2) * ZSTRIDE + jz] = s2;
        z_lds[(rbase + 3) * ZSTRIDE + jz] = s3;
        z_out[(size_t)(row0 + rbase + 0) * LAT + jz] = s0;
        z_out[(size_t)(row0 + rbase + 1) * LAT + jz] = s1;
        z_out[(size_t)(row0 + rbase + 2) * LAT + jz] = s2;
        z_out[(size_t)(row0 + rbase + 3) * LAT + jz] = s3;
    }
    __syncthreads();
    if (tid < BMf) {
        float zr[LAT];
        float zn = 0.f;
#pragma unroll
        for (int j = 0; j < LAT; ++j) {
            zr[j] = z_lds[tid * ZSTRIDE + j];
            zn = fmaf(zr[j], zr[j], zn);
        }
        float best = 3.4e38f;
        int bp = 0;
        for (int p = 0; p < NPROTO; ++p) {
            float dot = 0.f, pn = 0.f;
#pragma unroll
            for (int j = 0; j < LAT; ++j) {
                float pv = protos[p * LAT + j];
                dot = fmaf(zr[j], pv, dot);
                pn  = fmaf(pv, pv, pn);
            }
            float d = zn - 2.f * dot + pn;
            if (d < best) { best = d; bp = p; }
        }
        minidx_out[row0 + tid] = bp;
        minidx_lds[tid] = bp;
    }
    __syncthreads();
#pragma unroll
    for (int m = 0; m < 8; ++m) {
        int r = rg * 8 + m;
        somz_out[(size_t)(row0 + r) * LAT + jz] = protos[minidx_lds[r] * LAT + jz];
    }
}

__global__ __launch_bounds__(256)
void dpsom_gather(const float4* __restrict__ table,
                  const int* __restrict__ minidx,
                  float4* __restrict__ xrec)
{
    const int f = blockIdx.x * 256 + threadIdx.x;
    const int row = f / 196;
    const int c4  = f - row * 196;
    const int idx = minidx[row];
    xrec[f] = table[idx * 196 + c4];
}

// ================= launch =================
extern "C" void kernel_launch(void* const* d_in, const int* in_sizes, int n_in,
                              void* d_out, int out_size, void* d_ws, size_t ws_size,
                              hipStream_t stream)
{
    const float* x    = (const float*)d_in[0];
    const float* We1  = (const float*)d_in[1];
    const float* be1  = (const float*)d_in[2];
    const float* We2  = (const float*)d_in[3];
    const float* be2  = (const float*)d_in[4];
    const float* Wd1  = (const float*)d_in[5];
    const float* bd1  = (const float*)d_in[6];
    const float* Wd2  = (const float*)d_in[7];
    const float* bd2  = (const float*)d_in[8];
    const float* prot = (const float*)d_in[9];

    float* out   = (float*)d_out;
    float* xrec  = out;
    float* z_out = out + (size_t)BATCH * IN_DIM;
    float* somz  = z_out + (size_t)BATCH * LAT;

    if (ws_size >= WS_NEEDED) {
        unsigned short* B1 = (unsigned short*)d_ws;
        unsigned short* B2 = B1 + BT_SHORTS;
        unsigned short* B3 = B2 + BT_SHORTS;
        float* table = (float*)((char*)d_ws + 1228800);

        hipLaunchKernelGGL(prep_BF, dim3(100), dim3(256), 0, stream, We1, B1, B2, B3);
        hipLaunchKernelGGL(dpsom_dectab, dim3(NPROTO), dim3(256), 0, stream,
                           prot, Wd1, bd1, Wd2, bd2, table);
        hipLaunchKernelGGL(dpsom_encoder_bf3, dim3(BATCH / 64), dim3(256), 0, stream,
                           x, B1, B2, B3, be1, We2, be2, prot, table,
                           z_out, somz, xrec);
    } else {
        int*   minidx = (int*)d_ws;
        float* table  = (float*)((char*)d_ws + (size_t)BATCH * 4);
        hipLaunchKernelGGL(dpsom_encoder_fp32, dim3(BATCH / BMf), dim3(256), 0, stream,
                           x, We1, be1, We2, be2, prot, z_out, somz, minidx);
        hipLaunchKernelGGL(dpsom_dectab, dim3(NPROTO), dim3(256), 0, stream,
                           prot, Wd1, bd1, Wd2, bd2, table);
        hipLaunchKernelGGL(dpsom_gather, dim3((BATCH * (IN_DIM / 4)) / 256), dim3(256), 0, stream,
                           (const float4*)table, minidx, (float4*)xrec);
    }
}